// Round 15
// baseline (432.319 us; speedup 1.0000x reference)
//
#include <hip/hip_runtime.h>
#include <stdint.h>

#define BB 4096
#define TT 512
#define HH 32
#define SS 4

__device__ __forceinline__ float fast_sigm(float a) {
  return __builtin_amdgcn_rcpf(1.0f + __expf(-a));      // v_exp + v_rcp
}
__device__ __forceinline__ float fast_tanh(float y) {
  return 1.0f - 2.0f * __builtin_amdgcn_rcpf(__expf(2.0f * y) + 1.0f);
}

// Champion structure (r5/r7: 2 batches/wave, LDS h rows, deferred proj) with the
// 96 w_hh weights held in AGPRs via explicit v_accvgpr_write/read. The unified
// gfx950 register file gives 512 regs/wave; the RA refuses >96 ARCH VGPRs
// (r5-r12, 6 attempts) but explicit "a"-class values go to the accumulator
// side: register-file bandwidth for the weight stream, zero memory traffic,
// zero DS weight reads. GEMV = 96 accvgpr_read + 96 scalar FMA (no pkfma
// unions -> no operand-packing moves).
__global__ void __launch_bounds__(256, 2)
gru_kernel(const float* __restrict__ x, const float* __restrict__ h0,
           const float* __restrict__ w_ih, const float* __restrict__ w_hh,
           const float* __restrict__ b_ih, const float* __restrict__ b_hh,
           const float* __restrict__ w_proj, const float* __restrict__ b_proj,
           float* __restrict__ out) {
  const int tid  = threadIdx.x;
  const int wid  = tid >> 6;        // wave 0..3
  const int lane = tid & 63;
  const int g    = lane >> 5;       // batch within wave
  const int j    = lane & 31;       // h index owned by this lane
  const int row  = wid * 2 + g;     // LDS h row 0..7
  const int b    = blockIdx.x * 8 + row;
  const int s_idx = j & 3;          // proj channel
  const int c_idx = j >> 2;         // proj h-chunk

  __shared__ float lds_h[8][36];    // 144B row stride (conflict-free, r5-r14)
  float* lrow = &lds_h[row][0];
  const float4* lrow4 = (const float4*)lrow;
  const float* hc_addr = lrow + (c_idx << 2);

  // ---- stash all 96 w_hh weights into AGPRs ----
  float aw[96];                     // "a"-class after the asm writes
  const float4* whh4 = (const float4*)w_hh;
#pragma unroll
  for (int c = 0; c < 8; ++c) {
    const float4 tr = whh4[(0 * HH + j) * 8 + c];
    const float4 tz = whh4[(1 * HH + j) * 8 + c];
    const float4 tn = whh4[(2 * HH + j) * 8 + c];
    asm volatile("v_accvgpr_write_b32 %0, %1" : "=a"(aw[4*c+0])  : "v"(tr.x));
    asm volatile("v_accvgpr_write_b32 %0, %1" : "=a"(aw[4*c+1])  : "v"(tr.y));
    asm volatile("v_accvgpr_write_b32 %0, %1" : "=a"(aw[4*c+2])  : "v"(tr.z));
    asm volatile("v_accvgpr_write_b32 %0, %1" : "=a"(aw[4*c+3])  : "v"(tr.w));
    asm volatile("v_accvgpr_write_b32 %0, %1" : "=a"(aw[32+4*c+0]) : "v"(tz.x));
    asm volatile("v_accvgpr_write_b32 %0, %1" : "=a"(aw[32+4*c+1]) : "v"(tz.y));
    asm volatile("v_accvgpr_write_b32 %0, %1" : "=a"(aw[32+4*c+2]) : "v"(tz.z));
    asm volatile("v_accvgpr_write_b32 %0, %1" : "=a"(aw[32+4*c+3]) : "v"(tz.w));
    asm volatile("v_accvgpr_write_b32 %0, %1" : "=a"(aw[64+4*c+0]) : "v"(tn.x));
    asm volatile("v_accvgpr_write_b32 %0, %1" : "=a"(aw[64+4*c+1]) : "v"(tn.y));
    asm volatile("v_accvgpr_write_b32 %0, %1" : "=a"(aw[64+4*c+2]) : "v"(tn.z));
    asm volatile("v_accvgpr_write_b32 %0, %1" : "=a"(aw[64+4*c+3]) : "v"(tn.w));
  }

  // ---- small per-lane invariants (stay in arch VGPRs) ----
  const float4* wih4 = (const float4*)w_ih;
  const float4 wir = wih4[j], wiz = wih4[32 + j], win = wih4[64 + j];
  const float bir = b_ih[j], biz = b_ih[32 + j], bin_ = b_ih[64 + j];
  const float bhr = b_hh[j], bhz = b_hh[32 + j], bhn = b_hh[64 + j];
  const float4 wp = ((const float4*)w_proj)[s_idx * 8 + c_idx];
  const float bp = b_proj[s_idx];

  float h_self = h0[(size_t)b * HH + j];
  lrow[j] = h_self;

  const float4* xp = (const float4*)(x + (size_t)b * TT * 4);
  float* outp = out + (size_t)b * TT * SS;

  float4 xv = xp[0];

  for (int t = 0; t <= TT; ++t) {
    // h_{t-1} broadcast: 8x b128 uniform per group + per-lane proj chunk
    float4 h4[8];
#pragma unroll
    for (int c = 0; c < 8; ++c) h4[c] = lrow4[c];
    const float4 hcv = *(const float4*)hc_addr;

    // deferred projection: out[t-1] = proj(h after step t-1)
    if (t > 0) {
      float v = fmaf(wp.x, hcv.x, fmaf(wp.y, hcv.y,
                fmaf(wp.z, hcv.z, wp.w * hcv.w)));
      v += __shfl_xor(v, 4, 64);
      v += __shfl_xor(v, 8, 64);
      v += __shfl_xor(v, 16, 64);
      if (c_idx == 0) outp[(t - 1) * SS + s_idx] = v + bp;
    }
    if (t == TT) break;

    float4 xvn = xp[(t + 1 < TT) ? (t + 1) : t];   // next-step x prefetch

    // input gates (I=4)
    float xr = fmaf(wir.x, xv.x, fmaf(wir.y, xv.y, fmaf(wir.z, xv.z, fmaf(wir.w, xv.w, bir))));
    float xz = fmaf(wiz.x, xv.x, fmaf(wiz.y, xv.y, fmaf(wiz.z, xv.z, fmaf(wiz.w, xv.w, biz))));
    float xn = fmaf(win.x, xv.x, fmaf(win.y, xv.y, fmaf(win.z, xv.z, fmaf(win.w, xv.w, bin_))));

    // hidden GEMV: 96 accvgpr_read + 96 FMA, 3 independent accumulator chains
    float accr = bhr, accz = bhz, accn = bhn;
#pragma unroll
    for (int c = 0; c < 8; ++c) {
      float w0, w1, w2, w3;
      asm("v_accvgpr_read_b32 %0, %1" : "=v"(w0) : "a"(aw[4*c+0]));
      asm("v_accvgpr_read_b32 %0, %1" : "=v"(w1) : "a"(aw[4*c+1]));
      asm("v_accvgpr_read_b32 %0, %1" : "=v"(w2) : "a"(aw[4*c+2]));
      asm("v_accvgpr_read_b32 %0, %1" : "=v"(w3) : "a"(aw[4*c+3]));
      accr = fmaf(w0, h4[c].x, accr); accr = fmaf(w1, h4[c].y, accr);
      accr = fmaf(w2, h4[c].z, accr); accr = fmaf(w3, h4[c].w, accr);
      asm("v_accvgpr_read_b32 %0, %1" : "=v"(w0) : "a"(aw[32+4*c+0]));
      asm("v_accvgpr_read_b32 %0, %1" : "=v"(w1) : "a"(aw[32+4*c+1]));
      asm("v_accvgpr_read_b32 %0, %1" : "=v"(w2) : "a"(aw[32+4*c+2]));
      asm("v_accvgpr_read_b32 %0, %1" : "=v"(w3) : "a"(aw[32+4*c+3]));
      accz = fmaf(w0, h4[c].x, accz); accz = fmaf(w1, h4[c].y, accz);
      accz = fmaf(w2, h4[c].z, accz); accz = fmaf(w3, h4[c].w, accz);
      asm("v_accvgpr_read_b32 %0, %1" : "=v"(w0) : "a"(aw[64+4*c+0]));
      asm("v_accvgpr_read_b32 %0, %1" : "=v"(w1) : "a"(aw[64+4*c+1]));
      asm("v_accvgpr_read_b32 %0, %1" : "=v"(w2) : "a"(aw[64+4*c+2]));
      asm("v_accvgpr_read_b32 %0, %1" : "=v"(w3) : "a"(aw[64+4*c+3]));
      accn = fmaf(w0, h4[c].x, accn); accn = fmaf(w1, h4[c].y, accn);
      accn = fmaf(w2, h4[c].z, accn); accn = fmaf(w3, h4[c].w, accn);
    }

    const float r  = fast_sigm(xr + accr);
    const float zz = fast_sigm(xz + accz);
    const float nn = fast_tanh(fmaf(r, accn, xn));
    const float hnew = fmaf(zz, h_self - nn, nn);  // (1-z)n + z h
    h_self = hnew;

    lrow[j] = hnew;   // publish h_t (same-wave, in-order DS pipe)

    xv = xvn;
  }

  // hn output: [1, B, H] appended after state (f32)
  out[(size_t)BB * TT * SS + (size_t)b * HH + j] = h_self;
}

extern "C" void kernel_launch(void* const* d_in, const int* in_sizes, int n_in,
                              void* d_out, int out_size, void* d_ws, size_t ws_size,
                              hipStream_t stream) {
  const float* x      = (const float*)d_in[0];
  const float* h0     = (const float*)d_in[1];
  const float* w_ih   = (const float*)d_in[2];
  const float* w_hh   = (const float*)d_in[3];
  const float* b_ih   = (const float*)d_in[4];
  const float* b_hh   = (const float*)d_in[5];
  const float* w_proj = (const float*)d_in[6];
  const float* b_proj = (const float*)d_in[7];
  float* out = (float*)d_out;

  dim3 grid(BB / 8), block(256);
  hipLaunchKernelGGL(gru_kernel, grid, block, 0, stream,
                     x, h0, w_ih, w_hh, b_ih, b_hh, w_proj, b_proj, out);
}

// Round 17
// 390.464 us; speedup vs baseline: 1.1072x; 1.1072x over previous
//
#include <hip/hip_runtime.h>
#include <stdint.h>

#define BB 4096
#define TT 512
#define HH 32
#define SS 4

__device__ __forceinline__ float fast_sigm(float a) {
  return __builtin_amdgcn_rcpf(1.0f + __expf(-a));      // v_exp + v_rcp
}
__device__ __forceinline__ float fast_tanh(float y) {
  return 1.0f - 2.0f * __builtin_amdgcn_rcpf(__expf(2.0f * y) + 1.0f);
}

// Pack two f32 into one reg as f16 pair. asm volatile -> non-sinkable,
// non-rematerializable: the packed weights must stay live (r7 lesson).
#define PKH(dst, lo, hi)                                                       \
  asm volatile("v_cvt_pkrtz_f16_f32 %0, %1, %2" : "=v"(dst) : "v"(lo), "v"(hi))

// Mixed-precision FMA (VOP3P v_fma_mix_f32): acc += f16(w half) * f32(h).
// op_sel_hi[0]=1 -> S0 is f16; op_sel[0] picks lo/hi half. One instr per MAC,
// no unpack, weights at half register cost.
#define MIXLO(acc, w, h)                                                       \
  asm("v_fma_mix_f32 %0, %1, %2, %0 op_sel:[0,0,0] op_sel_hi:[1,0,0]"          \
      : "+v"(acc) : "v"(w), "v"(h))
#define MIXHI(acc, w, h)                                                       \
  asm("v_fma_mix_f32 %0, %1, %2, %0 op_sel:[1,0,0] op_sel_hi:[1,0,0]"          \
      : "+v"(acc) : "v"(w), "v"(h))

// Champion structure (2 batches/wave, LDS h rows, deferred proj) with ALL
// weights f16-packed in VGPRs: 96 w_hh -> 48 regs, w_ih -> 6, w_proj -> 2.
// Register demand ~108 vs the ~96 arch-VGPR allocator cap -> residual spill
// ~10 regs (vs 64 f32 spilled in the 292us champion). GEMV = 96 v_fma_mix_f32.
__global__ void __launch_bounds__(256, 2)
gru_kernel(const float* __restrict__ x, const float* __restrict__ h0,
           const float* __restrict__ w_ih, const float* __restrict__ w_hh,
           const float* __restrict__ b_ih, const float* __restrict__ b_hh,
           const float* __restrict__ w_proj, const float* __restrict__ b_proj,
           float* __restrict__ out) {
  const int tid  = threadIdx.x;
  const int wid  = tid >> 6;        // wave 0..3
  const int lane = tid & 63;
  const int g    = lane >> 5;       // batch within wave
  const int j    = lane & 31;       // h index owned by this lane
  const int row  = wid * 2 + g;     // LDS h row 0..7
  const int b    = blockIdx.x * 8 + row;
  const int s_idx = j & 3;          // proj channel
  const int c_idx = j >> 2;         // proj h-chunk

  __shared__ float lds_h[8][36];    // 144B row stride (conflict-free, r5-r15)
  float* lrow = &lds_h[row][0];
  const float4* lrow4 = (const float4*)lrow;
  const float* hc_addr = lrow + (c_idx << 2);

  // ---- pack w_hh rows j, j+32, j+64 into 48 f16-pair regs ----
  uint32_t wrp[16], wzp[16], wnp[16];
  const float4* whh4 = (const float4*)w_hh;
#pragma unroll
  for (int c = 0; c < 8; ++c) {
    const float4 tr = whh4[(0 * HH + j) * 8 + c];
    const float4 tz = whh4[(1 * HH + j) * 8 + c];
    const float4 tn = whh4[(2 * HH + j) * 8 + c];
    PKH(wrp[2*c],   tr.x, tr.y); PKH(wrp[2*c+1], tr.z, tr.w);
    PKH(wzp[2*c],   tz.x, tz.y); PKH(wzp[2*c+1], tz.z, tz.w);
    PKH(wnp[2*c],   tn.x, tn.y); PKH(wnp[2*c+1], tn.z, tn.w);
  }
  // ---- pack w_ih rows (I=4 -> 2 pairs per gate) and w_proj chunk ----
  uint32_t wip[6], wpp[2];
  {
    const float4* wih4 = (const float4*)w_ih;
    const float4 a = wih4[j], bq = wih4[32 + j], cq = wih4[64 + j];
    PKH(wip[0], a.x,  a.y);  PKH(wip[1], a.z,  a.w);
    PKH(wip[2], bq.x, bq.y); PKH(wip[3], bq.z, bq.w);
    PKH(wip[4], cq.x, cq.y); PKH(wip[5], cq.z, cq.w);
    const float4 p = ((const float4*)w_proj)[s_idx * 8 + c_idx];
    PKH(wpp[0], p.x, p.y); PKH(wpp[1], p.z, p.w);
  }

  const float bir = b_ih[j], biz = b_ih[32 + j], bin_ = b_ih[64 + j];
  const float bhr = b_hh[j], bhz = b_hh[32 + j], bhn = b_hh[64 + j];
  const float bp  = b_proj[s_idx];

  float h_self = h0[(size_t)b * HH + j];
  lrow[j] = h_self;

  const float4* xp = (const float4*)(x + (size_t)b * TT * 4);
  float* outp = out + (size_t)b * TT * SS;

  float4 xv = xp[0];

  for (int t = 0; t <= TT; ++t) {
    // h_{t-1} broadcast: 8x b128 uniform per group + per-lane proj chunk
    float4 h4[8];
#pragma unroll
    for (int c = 0; c < 8; ++c) h4[c] = lrow4[c];
    const float4 hcv = *(const float4*)hc_addr;

    // deferred projection: out[t-1] = proj(h after step t-1)
    if (t > 0) {
      float v = 0.0f;
      MIXLO(v, wpp[0], hcv.x); MIXHI(v, wpp[0], hcv.y);
      MIXLO(v, wpp[1], hcv.z); MIXHI(v, wpp[1], hcv.w);
      v += __shfl_xor(v, 4, 64);
      v += __shfl_xor(v, 8, 64);
      v += __shfl_xor(v, 16, 64);
      if (c_idx == 0) outp[(t - 1) * SS + s_idx] = v + bp;
    }
    if (t == TT) break;

    float4 xvn = xp[(t + 1 < TT) ? (t + 1) : t];   // next-step x prefetch

    // input gates (I=4): 12 fma_mix
    float xr = bir, xz = biz, xn = bin_;
    MIXLO(xr, wip[0], xv.x); MIXHI(xr, wip[0], xv.y);
    MIXLO(xr, wip[1], xv.z); MIXHI(xr, wip[1], xv.w);
    MIXLO(xz, wip[2], xv.x); MIXHI(xz, wip[2], xv.y);
    MIXLO(xz, wip[3], xv.z); MIXHI(xz, wip[3], xv.w);
    MIXLO(xn, wip[4], xv.x); MIXHI(xn, wip[4], xv.y);
    MIXLO(xn, wip[5], xv.z); MIXHI(xn, wip[5], xv.w);

    // hidden GEMV: exactly 96 fma_mix, r/z/n chains interleaved
    float accr = bhr, accz = bhz, accn = bhn;
#pragma unroll
    for (int c = 0; c < 8; ++c) {
      MIXLO(accr, wrp[2*c],   h4[c].x);
      MIXLO(accz, wzp[2*c],   h4[c].x);
      MIXLO(accn, wnp[2*c],   h4[c].x);
      MIXHI(accr, wrp[2*c],   h4[c].y);
      MIXHI(accz, wzp[2*c],   h4[c].y);
      MIXHI(accn, wnp[2*c],   h4[c].y);
      MIXLO(accr, wrp[2*c+1], h4[c].z);
      MIXLO(accz, wzp[2*c+1], h4[c].z);
      MIXLO(accn, wnp[2*c+1], h4[c].z);
      MIXHI(accr, wrp[2*c+1], h4[c].w);
      MIXHI(accz, wzp[2*c+1], h4[c].w);
      MIXHI(accn, wnp[2*c+1], h4[c].w);
    }

    const float r  = fast_sigm(xr + accr);
    const float zz = fast_sigm(xz + accz);
    const float nn = fast_tanh(fmaf(r, accn, xn));
    const float hnew = fmaf(zz, h_self - nn, nn);  // (1-z)n + z h
    h_self = hnew;

    lrow[j] = hnew;   // publish h_t (same-wave, in-order DS pipe)

    xv = xvn;
  }

  // hn output: [1, B, H] appended after state (f32)
  out[(size_t)BB * TT * SS + (size_t)b * HH + j] = h_self;
}

extern "C" void kernel_launch(void* const* d_in, const int* in_sizes, int n_in,
                              void* d_out, int out_size, void* d_ws, size_t ws_size,
                              hipStream_t stream) {
  const float* x      = (const float*)d_in[0];
  const float* h0     = (const float*)d_in[1];
  const float* w_ih   = (const float*)d_in[2];
  const float* w_hh   = (const float*)d_in[3];
  const float* b_ih   = (const float*)d_in[4];
  const float* b_hh   = (const float*)d_in[5];
  const float* w_proj = (const float*)d_in[6];
  const float* b_proj = (const float*)d_in[7];
  float* out = (float*)d_out;

  dim3 grid(BB / 8), block(256);
  hipLaunchKernelGGL(gru_kernel, grid, block, 0, stream,
                     x, h0, w_ih, w_hh, b_ih, b_hh, w_proj, b_proj, out);
}